// Round 16
// baseline (197.199 us; speedup 1.0000x reference)
//
#include <hip/hip_runtime.h>

namespace {

constexpr int BATCH = 256;
constexpr int S_IN  = 256;
constexpr int NNEUR = 128;
constexpr int NSYN  = 256;
constexpr int MOUT  = 256;
constexpr float NO_SPIKE_T = 1.0e30f; // finite sentinel (ref holds inf; inf-inf=nan fails)
constexpr float K1  = 0.72134752044448170f;  // log2(e)/2  : exp(t/2) = 2^(K1*t)
constexpr float NL2 = -1.3862943611198906f;  // -2*ln2     : t = NL2*log2(z)
constexpr float ZEPS = (float)(1.0 - 1e-6);
constexpr float Z20F = 4.5399929762484854e-05f;  // e^-10  (t=20 bound in z-space)

// dynamic LDS layout (bytes)
constexpr int LDS_WR4   = 0;                       // float4 wr4[128*64] = 131072
constexpr int LDS_EV    = 131072;                  // float4 ev[264]     = 4224
constexpr int LDS_SPK   = 135296;                  // int spk[264]       = 1056
constexpr int LDS_SS    = 136352;                  // int ss[272]        = 1088
constexpr int LDS_LT    = 137440;                  // float lt[256]      = 1024
constexpr int LDS_TOTAL = 138464;

__device__ __forceinline__ float hw_exp2(float x) { return __builtin_amdgcn_exp2f(x); }
__device__ __forceinline__ float hw_log2(float x) { return __builtin_amdgcn_logf(x); }
__device__ __forceinline__ float hw_rcp(float x)  { return __builtin_amdgcn_rcpf(x); }

// transpose wff (N,NSYN)->(NSYN,N) and (optionally) wrec (N,N)->(N,N)^T
__global__ void transpose_kernel(const float* __restrict__ wff,
                                 const float* __restrict__ wrec,
                                 float* __restrict__ wffT,
                                 float* __restrict__ wrecT,
                                 int do_wrec) {
    int i = blockIdx.x * blockDim.x + threadIdx.x;   // 32768 threads
    {
        int s = i >> 7;
        int n = i & (NNEUR - 1);
        wffT[i] = wff[n * NSYN + s];
    }
    if (do_wrec && i < NNEUR * NNEUR) {
        int j = i >> 7;
        int n = i & (NNEUR - 1);
        wrecT[i] = wrec[n * NNEUR + j];
    }
}

template <int CTRL>
__device__ __forceinline__ int dpp_imax(int v) {
    int t = __builtin_amdgcn_update_dpp(v, v, CTRL, 0xf, 0xf, false);
    return (t > v) ? t : v;
}

// z-space candidate: largest valid root z of A z - B z^2 = 1 in (1e-12, zlim).
// z2 >= z1; t = -2 ln z decreasing in z, so max valid z == min t. Invalid -> 0.
// nan inputs (post-freeze poison) -> all compares false -> 0.
__device__ __forceinline__ float cand_z(float A, float B, float zlim) {
    float disc = __builtin_fmaf(A, A, -4.0f * B);
    float r2B  = hw_rcp(B + B);
    float sq   = __fsqrt_rn(disc);
    float z2 = (A + sq) * r2B;
    float z1 = (A - sq) * r2B;
    bool okd = (disc > 0.0f) & (B > 1e-12f);
    bool v2 = okd & (z2 > 1e-12f) & (z2 < zlim);
    bool v1 = okd & (z1 > 1e-12f) & (z1 < zlim);
    return v2 ? z2 : (v1 ? z1 : 0.0f);
}

__global__ __launch_bounds__(64, 1) void lif_event_kernel(
    const float* __restrict__ in_t,
    const int*   __restrict__ in_sid,
    const float* __restrict__ wff,    // (N,NSYN) original, fallback
    const float* __restrict__ wffT,   // (NSYN,N) transposed, preferred
    const float* __restrict__ wrec,   // (N,N) original, fallback staging source
    const float* __restrict__ wrecT,  // (N,N)^T, preferred staging source
    int use_t, int use_wt,
    float* __restrict__ out_t,
    float* __restrict__ out_id)
{
    extern __shared__ char smem[];
    float4* wr4   = (float4*)(smem + LDS_WR4);   // [(127-j)*64+half] = {wA0,wA1,wB0,wB1}
    float4* evL   = (float4*)(smem + LDS_EV);
    int*    spkI  = (int*)   (smem + LDS_SPK);
    int*    ssL   = (int*)   (smem + LDS_SS);
    float*  lt    = (float*) (smem + LDS_LT);

    const int b = blockIdx.x;
    const int lane = threadIdx.x;

    // ---- stage combined Wrec layout into LDS ----
    // coalesced float2 reads from wrecT rows, contiguous b128 LDS writes.
    for (int c = lane; c < NNEUR * 64; c += 64) {
        const int j = c >> 6;          // source column of wrec
        const int half = c & 63;       // lane-pair index (neurons 2*half, 2*half+1)
        const int na = 2 * half, nb = na + 1;
        float w0, w1;
        if (use_wt) {
            float2 w = *(const float2*)&wrecT[j * NNEUR + na];
            w0 = w.x; w1 = w.y;
        } else {
            w0 = wrec[na * NNEUR + j];
            w1 = wrec[nb * NNEUR + j];
        }
        wr4[(127 - j) * 64 + half] = make_float4(
            w0 - ((na == j) ? 1.0f : 0.0f),
            w1 - ((nb == j) ? 1.0f : 0.0f),
            w0, w1);
    }

    // ---- load events; stable rank sort; precompute per-event exponentials ----
    float myt[4]; int mys[4];
    for (int q = 0; q < 4; ++q) {
        int k = lane + 64 * q;
        myt[q] = in_t[b * S_IN + k];
        mys[q] = in_sid[b * S_IN + k];
        lt[k] = myt[q];
    }
    __syncthreads();
    int rk[4] = {0, 0, 0, 0};
    for (int j = 0; j < S_IN; ++j) {
        float tj = lt[j];
        #pragma unroll
        for (int q = 0; q < 4; ++q)
            rk[q] += (tj < myt[q] || (tj == myt[q] && j < lane + 64 * q)) ? 1 : 0;
    }
    for (int q = 0; q < 4; ++q) {
        float t = myt[q];
        float zi = hw_exp2(-K1 * t);    // z_in = exp(-t/2)
        float e  = hw_exp2(K1 * t);     // exp(t/2)
        evL[rk[q]] = make_float4(__builtin_bit_cast(float, mys[q]), zi, e, e * e);
        ssL[rk[q]] = mys[q];
    }
    if (lane < 8)  evL[S_IN + lane] = make_float4(0.0f, 0.0f, 1.0f, 1.0f);  // pad: t=inf -> z=0
    if (lane < 16) ssL[S_IN + lane] = 0;
    __syncthreads();

    const int n0 = lane * 2;
    const int n1 = n0 + 1;
    const int KZ20 = __builtin_bit_cast(int, Z20F) & ~127;

    float A0 = 0.f, A1 = 0.f, B0 = 0.f, B1 = 0.f;
    int ptr = 0, cnt = 0;
    float zlim = ZEPS;   // z_cur = 1

#define LOADW(dst, sid_)                                                     \
    do {                                                                     \
        const int s_ = (sid_);                                               \
        if (use_t) dst = *(const float2*)&wffT[s_ * NNEUR + n0];             \
        else       dst = make_float2(wff[n0 * NSYN + s_], wff[n1 * NSYN + s_]); \
    } while (0)

// wave argmax key from the two per-lane candidates; ties -> lowest neuron idx
#define REDUCE_KEY2(kk, zb0_, zb1_)                                          \
    do {                                                                     \
        int ka_ = (__builtin_bit_cast(int, (zb0_)) & ~127) | (127 - n0);     \
        int kb_ = (__builtin_bit_cast(int, (zb1_)) & ~127) | (127 - n1);     \
        int key_ = (kb_ > ka_) ? kb_ : ka_;                                  \
        key_ = dpp_imax<0x111>(key_);                                        \
        key_ = dpp_imax<0x112>(key_);                                        \
        key_ = dpp_imax<0x114>(key_);                                        \
        key_ = dpp_imax<0x118>(key_);                                        \
        key_ = dpp_imax<0x142>(key_);                                        \
        key_ = dpp_imax<0x143>(key_);                                        \
        kk = __builtin_amdgcn_readlane(key_, 63);                            \
    } while (0)

// emit update from uniform key: ONE contiguous b128 LDS read (conflict-free);
// em/es transcendentals overlap the read
#define APPLY_EMIT(kk)                                                       \
    do {                                                                     \
        const int jr_ = (kk) & 127;                                          \
        const float zmax_ = __builtin_bit_cast(float, (kk) & ~127);          \
        const float4 wr_ = wr4[jr_ * 64 + lane];                             \
        const float em_ = hw_rcp(zmax_);                                     \
        const float es_ = hw_rcp(zmax_ * zmax_);                             \
        A0 = __builtin_fmaf(wr_.x, em_, A0);                                 \
        A1 = __builtin_fmaf(wr_.y, em_, A1);                                 \
        B0 = __builtin_fmaf(wr_.z, es_, B0);                                 \
        B1 = __builtin_fmaf(wr_.w, es_, B1);                                 \
        zlim = ZEPS * zmax_;                                                 \
    } while (0)

#define EMIT_STEP(kk)                                                        \
    do {                                                                     \
        const float zb0_ = cand_z(A0, B0, zlim);                             \
        const float zb1_ = cand_z(A1, B1, zlim);                             \
        REDUCE_KEY2(kk, zb0_, zb1_);                                         \
        APPLY_EMIT(kk);                                                      \
    } while (0)

    // ---- event pipeline: ev0..3 (full data), w0..7 (weights for events
    //      ptr..ptr+7), sP0..3 (sids for events ptr+8..ptr+11) ----
    float4 ev0 = evL[0], ev1 = evL[1], ev2 = evL[2], ev3 = evL[3];
    float2 w0, w1, w2, w3, w4, w5, w6, w7;
    LOADW(w0, ssL[0]); LOADW(w1, ssL[1]); LOADW(w2, ssL[2]); LOADW(w3, ssL[3]);
    LOADW(w4, ssL[4]); LOADW(w5, ssL[5]); LOADW(w6, ssL[6]); LOADW(w7, ssL[7]);
    int sP0 = ssL[8], sP1 = ssL[9], sP2 = ssL[10], sP3 = ssL[11];

    // ================= PHASE 1: quad-consume, deep weight prefetch =================
    while (ptr + 4 <= S_IN && cnt < MOUT) {
        const float zb0 = cand_z(A0, B0, zlim);
        const float zb1 = cand_z(A1, B1, zlim);
        const float zc = fmaxf(zb0, zb1);
        int key;
        REDUCE_KEY2(key, zb0, zb1);

        // speculative post-consume states S1..S3 (sequential FMA = ref rounding)
        const float A0p = __builtin_fmaf(w0.x, ev0.z, A0);
        const float A1p = __builtin_fmaf(w0.y, ev0.z, A1);
        const float B0p = __builtin_fmaf(w0.x, ev0.w, B0);
        const float B1p = __builtin_fmaf(w0.y, ev0.w, B1);
        const float zl1 = ZEPS * ev0.y;
        const float zc1 = fmaxf(cand_z(A0p, B0p, zl1), cand_z(A1p, B1p, zl1));

        const float A0q = __builtin_fmaf(w1.x, ev1.z, A0p);
        const float A1q = __builtin_fmaf(w1.y, ev1.z, A1p);
        const float B0q = __builtin_fmaf(w1.x, ev1.w, B0p);
        const float B1q = __builtin_fmaf(w1.y, ev1.w, B1p);
        const float zl2 = ZEPS * ev1.y;
        const float zc2 = fmaxf(cand_z(A0q, B0q, zl2), cand_z(A1q, B1q, zl2));

        const float A0r = __builtin_fmaf(w2.x, ev2.z, A0q);
        const float A1r = __builtin_fmaf(w2.y, ev2.z, A1q);
        const float B0r = __builtin_fmaf(w2.x, ev2.w, B0q);
        const float B1r = __builtin_fmaf(w2.y, ev2.w, B1q);
        const float zl3 = ZEPS * ev2.y;
        const float zc3 = fmaxf(cand_z(A0r, B0r, zl3), cand_z(A1r, B1r, zl3));

        const unsigned long long m0 = __ballot((zc  > ev0.y) & (zc  > Z20F));
        const unsigned long long m1 = __ballot((zc1 > ev1.y) & (zc1 > Z20F));
        const unsigned long long m2 = __ballot((zc2 > ev2.y) & (zc2 > Z20F));
        const unsigned long long m3 = __ballot((zc3 > ev3.y) & (zc3 > Z20F));

        if (m0 != 0ull) {
            APPLY_EMIT(key);
            if (lane == 0) spkI[cnt] = key;
            ++cnt;
        } else if (m1 != 0ull) {
            A0 = A0p; A1 = A1p; B0 = B0p; B1 = B1p; zlim = zl1; ptr += 1;
            ev0 = ev1; ev1 = ev2; ev2 = ev3; ev3 = evL[ptr + 3];
            w0 = w1; w1 = w2; w2 = w3; w3 = w4; w4 = w5; w5 = w6; w6 = w7;
            LOADW(w7, sP0);
            sP0 = sP1; sP1 = sP2; sP2 = sP3; sP3 = ssL[ptr + 11];
        } else if (m2 != 0ull) {
            A0 = A0q; A1 = A1q; B0 = B0q; B1 = B1q; zlim = zl2; ptr += 2;
            ev0 = ev2; ev1 = ev3; ev2 = evL[ptr + 2]; ev3 = evL[ptr + 3];
            w0 = w2; w1 = w3; w2 = w4; w3 = w5; w4 = w6; w5 = w7;
            LOADW(w6, sP0); LOADW(w7, sP1);
            sP0 = sP2; sP1 = sP3; sP2 = ssL[ptr + 10]; sP3 = ssL[ptr + 11];
        } else if (m3 != 0ull) {
            A0 = A0r; A1 = A1r; B0 = B0r; B1 = B1r; zlim = zl3; ptr += 3;
            ev0 = ev3; ev1 = evL[ptr + 1]; ev2 = evL[ptr + 2]; ev3 = evL[ptr + 3];
            w0 = w3; w1 = w4; w2 = w5; w3 = w6; w4 = w7;
            LOADW(w5, sP0); LOADW(w6, sP1); LOADW(w7, sP2);
            sP0 = sP3; sP1 = ssL[ptr + 9]; sP2 = ssL[ptr + 10]; sP3 = ssL[ptr + 11];
        } else {
            A0 = __builtin_fmaf(w3.x, ev3.z, A0r);
            A1 = __builtin_fmaf(w3.y, ev3.z, A1r);
            B0 = __builtin_fmaf(w3.x, ev3.w, B0r);
            B1 = __builtin_fmaf(w3.y, ev3.w, B1r);
            zlim = ZEPS * ev3.y; ptr += 4;
            ev0 = evL[ptr]; ev1 = evL[ptr + 1]; ev2 = evL[ptr + 2]; ev3 = evL[ptr + 3];
            w0 = w4; w1 = w5; w2 = w6; w3 = w7;
            LOADW(w4, sP0); LOADW(w5, sP1); LOADW(w6, sP2); LOADW(w7, sP3);
            sP0 = ssL[ptr + 8]; sP1 = ssL[ptr + 9]; sP2 = ssL[ptr + 10]; sP3 = ssL[ptr + 11];
        }
    }

    // ---- tail: single-step until inputs exhausted ----
    while (ptr < S_IN && cnt < MOUT) {
        const float zb0 = cand_z(A0, B0, zlim);
        const float zb1 = cand_z(A1, B1, zlim);
        const float zc = fmaxf(zb0, zb1);
        int key;
        REDUCE_KEY2(key, zb0, zb1);
        const unsigned long long m = __ballot((zc > ev0.y) & (zc > Z20F));
        if (m != 0ull) {
            APPLY_EMIT(key);
            if (lane == 0) spkI[cnt] = key;
            ++cnt;
        } else {
            A0 = __builtin_fmaf(w0.x, ev0.z, A0);
            A1 = __builtin_fmaf(w0.y, ev0.z, A1);
            B0 = __builtin_fmaf(w0.x, ev0.w, B0);
            B1 = __builtin_fmaf(w0.y, ev0.w, B1);
            zlim = ZEPS * ev0.y;
            ++ptr;
            ev0 = ev1; ev1 = ev2; ev2 = ev3; ev3 = evL[ptr + 3];
            w0 = w1; w1 = w2; w2 = w3; w3 = w4; w4 = w5; w5 = w6; w6 = w7;
            LOADW(w7, sP0);
            sP0 = sP1; sP1 = sP2; sP2 = sP3; sP3 = ssL[ptr + 11];
        }
    }

    // ===== PHASE 2: pure emit drain — branchless 8-unrolled blocks =====
    // Frozen state self-poisons safely (zc->0, key zmax-bits <= KZ20, nan stays 0);
    // bogus sub-emits past the freeze point excluded via cnt += p.
    while (cnt < MOUT) {
        int k0, k1, k2, k3, k4, k5, k6, k7;
        EMIT_STEP(k0); EMIT_STEP(k1); EMIT_STEP(k2); EMIT_STEP(k3);
        EMIT_STEP(k4); EMIT_STEP(k5); EMIT_STEP(k6); EMIT_STEP(k7);
        if (lane == 0) {
            spkI[cnt + 0] = k0; spkI[cnt + 1] = k1;
            spkI[cnt + 2] = k2; spkI[cnt + 3] = k3;
            spkI[cnt + 4] = k4; spkI[cnt + 5] = k5;
            spkI[cnt + 6] = k6; spkI[cnt + 7] = k7;
        }
        const bool f0 = (k0 & ~127) <= KZ20;
        const bool f1 = (k1 & ~127) <= KZ20;
        const bool f2 = (k2 & ~127) <= KZ20;
        const bool f3 = (k3 & ~127) <= KZ20;
        const bool f4 = (k4 & ~127) <= KZ20;
        const bool f5 = (k5 & ~127) <= KZ20;
        const bool f6 = (k6 & ~127) <= KZ20;
        const bool f7 = (k7 & ~127) <= KZ20;
        const int p = f0 ? 0 : (f1 ? 1 : (f2 ? 2 : (f3 ? 3 :
                      (f4 ? 4 : (f5 ? 5 : (f6 ? 6 : (f7 ? 7 : 8)))))));
        cnt += p;
        if (p < 8) break;
    }
    if (cnt > MOUT) cnt = MOUT;
#undef LOADW
#undef REDUCE_KEY2
#undef APPLY_EMIT
#undef EMIT_STEP

    // ---- flush: decode keys -> (t, id), fill the rest (every call) ----
    __syncthreads();
    for (int k = lane; k < MOUT; k += 64) {
        const int kk = spkI[k];
        const bool live = (k < cnt);
        const float zmax = __builtin_bit_cast(float, kk & ~127);
        const float t = NL2 * hw_log2(zmax);
        const float id = (float)(127 - (kk & 127));
        out_t[b * MOUT + k]  = live ? t : NO_SPIKE_T;
        out_id[b * MOUT + k] = live ? id : -1.0f;
    }
}

} // namespace

extern "C" void kernel_launch(void* const* d_in, const int* in_sizes, int n_in,
                              void* d_out, int out_size, void* d_ws, size_t ws_size,
                              hipStream_t stream) {
    (void)in_sizes; (void)n_in; (void)out_size;
    const float* in_t   = (const float*)d_in[0];
    const int*   in_sid = (const int*)d_in[1];
    const float* wff    = (const float*)d_in[2];
    const float* wrec   = (const float*)d_in[3];

    float* out_t  = (float*)d_out;
    float* out_id = (float*)d_out + BATCH * MOUT;

    float* wffT  = (float*)d_ws;
    float* wrecT = wffT + NSYN * NNEUR;
    const size_t need1 = (size_t)(NSYN * NNEUR) * sizeof(float);
    const size_t need2 = need1 + (size_t)(NNEUR * NNEUR) * sizeof(float);
    const int use_t  = (ws_size >= need1) ? 1 : 0;
    const int use_wt = (ws_size >= need2) ? 1 : 0;

    if (use_t) {
        transpose_kernel<<<(NSYN * NNEUR) / 256, 256, 0, stream>>>(
            wff, wrec, wffT, wrecT, use_wt);
    }
    lif_event_kernel<<<BATCH, 64, LDS_TOTAL, stream>>>(
        in_t, in_sid, wff, wffT, wrec, wrecT, use_t, use_wt, out_t, out_id);
}

// Round 17
// 163.244 us; speedup vs baseline: 1.2080x; 1.2080x over previous
//
#include <hip/hip_runtime.h>

namespace {

constexpr int BATCH = 256;
constexpr int S_IN  = 256;
constexpr int NNEUR = 128;
constexpr int NSYN  = 256;
constexpr int MOUT  = 256;
constexpr int WSTR  = 130;            // padded LDS stride (2-way bank aliasing = free)
constexpr float NO_SPIKE_T = 1.0e30f; // finite sentinel (ref holds inf; inf-inf=nan fails)
constexpr float K1  = 0.72134752044448170f;  // log2(e)/2  : exp(t/2) = 2^(K1*t)
constexpr float NL2 = -1.3862943611198906f;  // -2*ln2     : t = NL2*log2(z)
constexpr float ZEPS = (float)(1.0 - 1e-6);
constexpr float Z20F = 4.5399929762484854e-05f;  // e^-10  (t=20 bound in z-space)

// dynamic LDS layout (bytes)
constexpr int LDS_WREC  = 0;                       // wrecL[128*130]f = 66560
constexpr int LDS_EV    = 66560;                   // float4 ev[264] = 4224
constexpr int LDS_SPK   = LDS_EV + 4224;           // int spk[264]   = 1056
constexpr int LDS_LT    = LDS_SPK + 1056;          // float lt[256]  = 1024
constexpr int LDS_TOTAL = LDS_LT + 1024;           // 72864

__device__ __forceinline__ float hw_exp2(float x) { return __builtin_amdgcn_exp2f(x); }
__device__ __forceinline__ float hw_log2(float x) { return __builtin_amdgcn_logf(x); }
__device__ __forceinline__ float hw_rcp(float x)  { return __builtin_amdgcn_rcpf(x); }

__global__ void transpose_wff_kernel(const float* __restrict__ wff,
                                     float* __restrict__ wffT) {
    int i = blockIdx.x * blockDim.x + threadIdx.x;   // 32768 threads
    int s = i >> 7;
    int n = i & (NNEUR - 1);
    wffT[i] = wff[n * NSYN + s];
}

template <int CTRL>
__device__ __forceinline__ int dpp_imax(int v) {
    int t = __builtin_amdgcn_update_dpp(v, v, CTRL, 0xf, 0xf, false);
    return (t > v) ? t : v;
}

// z-space candidate: largest valid root z of A z - B z^2 = 1 in (1e-12, zlim).
// z2 >= z1; t = -2 ln z decreasing in z, so max valid z == min t. Invalid -> 0.
// nan inputs (post-freeze poison) -> all compares false -> 0.
__device__ __forceinline__ float cand_z(float A, float B, float zlim) {
    float disc = __builtin_fmaf(A, A, -4.0f * B);
    float r2B  = hw_rcp(B + B);
    float sq   = __fsqrt_rn(disc);
    float z2 = (A + sq) * r2B;
    float z1 = (A - sq) * r2B;
    bool okd = (disc > 0.0f) & (B > 1e-12f);
    bool v2 = okd & (z2 > 1e-12f) & (z2 < zlim);
    bool v1 = okd & (z1 > 1e-12f) & (z1 < zlim);
    return v2 ? z2 : (v1 ? z1 : 0.0f);
}

__global__ __launch_bounds__(64, 1) void lif_event_kernel(
    const float* __restrict__ in_t,
    const int*   __restrict__ in_sid,
    const float* __restrict__ wff,    // (N,NSYN) original, fallback
    const float* __restrict__ wffT,   // (NSYN,N) transposed, preferred
    const float* __restrict__ wrec,   // (N,N) original; staged->LDS transposed
    int use_t,
    float* __restrict__ out_t,
    float* __restrict__ out_id)
{
    extern __shared__ char smem[];
    float*  wrecL = (float*)(smem + LDS_WREC);   // [j*WSTR + n] = wrec[n][j]
    float4* evL   = (float4*)(smem + LDS_EV);
    int*    spkI  = (int*)   (smem + LDS_SPK);
    float*  lt    = (float*) (smem + LDS_LT);

    const int b = blockIdx.x;
    const int lane = threadIdx.x;

    // ---- stage WrecT into LDS (R13 pattern) ----
    const float4* wrec4 = (const float4*)wrec;
    for (int i = lane; i < NNEUR * NNEUR / 4; i += 64) {
        float4 v = wrec4[i];
        int n  = i >> 5;
        int c0 = (i & 31) * 4;
        wrecL[(c0 + 0) * WSTR + n] = v.x;
        wrecL[(c0 + 1) * WSTR + n] = v.y;
        wrecL[(c0 + 2) * WSTR + n] = v.z;
        wrecL[(c0 + 3) * WSTR + n] = v.w;
    }

    // ---- load events; stable rank sort; precompute per-event exponentials ----
    float myt[4]; int mys[4];
    for (int q = 0; q < 4; ++q) {
        int k = lane + 64 * q;
        myt[q] = in_t[b * S_IN + k];
        mys[q] = in_sid[b * S_IN + k];
        lt[k] = myt[q];
    }
    __syncthreads();
    int rk[4] = {0, 0, 0, 0};
    for (int j = 0; j < S_IN; ++j) {
        float tj = lt[j];
        #pragma unroll
        for (int q = 0; q < 4; ++q)
            rk[q] += (tj < myt[q] || (tj == myt[q] && j < lane + 64 * q)) ? 1 : 0;
    }
    for (int q = 0; q < 4; ++q) {
        float t = myt[q];
        float zi = hw_exp2(-K1 * t);    // z_in = exp(-t/2)
        float e  = hw_exp2(K1 * t);     // exp(t/2)
        evL[rk[q]] = make_float4(__builtin_bit_cast(float, mys[q]), zi, e, e * e);
    }
    if (lane < 8) evL[S_IN + lane] = make_float4(0.0f, 0.0f, 1.0f, 1.0f);  // pad: t=inf -> z=0
    __syncthreads();

    const int n0 = lane * 2;
    const int n1 = n0 + 1;
    const int KZ20 = __builtin_bit_cast(int, Z20F) & ~127;

    float A0 = 0.f, A1 = 0.f, B0 = 0.f, B1 = 0.f;
    int ptr = 0, cnt = 0;
    float zlim = ZEPS;   // z_cur = 1

#define LOADW(dst, sid_)                                                     \
    do {                                                                     \
        const int s_ = (sid_);                                               \
        if (use_t) dst = *(const float2*)&wffT[s_ * NNEUR + n0];             \
        else       dst = make_float2(wff[n0 * NSYN + s_], wff[n1 * NSYN + s_]); \
    } while (0)

// wave argmax key from the two per-lane candidates; ties -> lowest neuron idx
#define REDUCE_KEY2(kk, zb0_, zb1_)                                          \
    do {                                                                     \
        int ka_ = (__builtin_bit_cast(int, (zb0_)) & ~127) | (127 - n0);     \
        int kb_ = (__builtin_bit_cast(int, (zb1_)) & ~127) | (127 - n1);     \
        int key_ = (kb_ > ka_) ? kb_ : ka_;                                  \
        key_ = dpp_imax<0x111>(key_);                                        \
        key_ = dpp_imax<0x112>(key_);                                        \
        key_ = dpp_imax<0x114>(key_);                                        \
        key_ = dpp_imax<0x118>(key_);                                        \
        key_ = dpp_imax<0x142>(key_);                                        \
        key_ = dpp_imax<0x143>(key_);                                        \
        kk = __builtin_amdgcn_readlane(key_, 63);                            \
    } while (0)

// emit update from uniform key: one b64 LDS read (2-way aliased = free);
// em and es via two PARALLEL rcp's, both overlapping the LDS read
#define APPLY_EMIT(kk)                                                       \
    do {                                                                     \
        const int jn_ = 127 - ((kk) & 127);                                  \
        const float zmax_ = __builtin_bit_cast(float, (kk) & ~127);          \
        const float2 wr_ = *(const float2*)&wrecL[jn_ * WSTR + n0];          \
        const float em_ = hw_rcp(zmax_);                                     \
        const float es_ = hw_rcp(zmax_ * zmax_);                             \
        const float r0_ = (n0 == jn_) ? 1.0f : 0.0f;                         \
        const float r1_ = (n1 == jn_) ? 1.0f : 0.0f;                         \
        A0 = __builtin_fmaf(wr_.x - r0_, em_, A0);                           \
        A1 = __builtin_fmaf(wr_.y - r1_, em_, A1);                           \
        B0 = __builtin_fmaf(wr_.x, es_, B0);                                 \
        B1 = __builtin_fmaf(wr_.y, es_, B1);                                 \
        zlim = ZEPS * zmax_;                                                 \
    } while (0)

#define EMIT_STEP(kk)                                                        \
    do {                                                                     \
        const float zb0_ = cand_z(A0, B0, zlim);                             \
        const float zb1_ = cand_z(A1, B1, zlim);                             \
        REDUCE_KEY2(kk, zb0_, zb1_);                                         \
        APPLY_EMIT(kk);                                                      \
    } while (0)

    // ---- event slots A..D = events ptr..ptr+3, weights prefetched ----
    float4 evA = evL[0], evB = evL[1], evC = evL[2], evD = evL[3];
    float2 wA, wB, wC, wD;
    LOADW(wA, __builtin_bit_cast(int, evA.x));
    LOADW(wB, __builtin_bit_cast(int, evB.x));
    LOADW(wC, __builtin_bit_cast(int, evC.x));
    LOADW(wD, __builtin_bit_cast(int, evD.x));

    // ================= PHASE 1: quad-consume =================
    while (ptr + 4 <= S_IN && cnt < MOUT) {
        const float zb0 = cand_z(A0, B0, zlim);
        const float zb1 = cand_z(A1, B1, zlim);
        const float zc = fmaxf(zb0, zb1);
        int key;
        REDUCE_KEY2(key, zb0, zb1);

        // speculative post-consume states S1..S3 (sequential FMA = ref rounding)
        const float A0p = __builtin_fmaf(wA.x, evA.z, A0);
        const float A1p = __builtin_fmaf(wA.y, evA.z, A1);
        const float B0p = __builtin_fmaf(wA.x, evA.w, B0);
        const float B1p = __builtin_fmaf(wA.y, evA.w, B1);
        const float zl1 = ZEPS * evA.y;
        const float zc1 = fmaxf(cand_z(A0p, B0p, zl1), cand_z(A1p, B1p, zl1));

        const float A0q = __builtin_fmaf(wB.x, evB.z, A0p);
        const float A1q = __builtin_fmaf(wB.y, evB.z, A1p);
        const float B0q = __builtin_fmaf(wB.x, evB.w, B0p);
        const float B1q = __builtin_fmaf(wB.y, evB.w, B1p);
        const float zl2 = ZEPS * evB.y;
        const float zc2 = fmaxf(cand_z(A0q, B0q, zl2), cand_z(A1q, B1q, zl2));

        const float A0r = __builtin_fmaf(wC.x, evC.z, A0q);
        const float A1r = __builtin_fmaf(wC.y, evC.z, A1q);
        const float B0r = __builtin_fmaf(wC.x, evC.w, B0q);
        const float B1r = __builtin_fmaf(wC.y, evC.w, B1q);
        const float zl3 = ZEPS * evC.y;
        const float zc3 = fmaxf(cand_z(A0r, B0r, zl3), cand_z(A1r, B1r, zl3));

        const unsigned long long m0 = __ballot((zc  > evA.y) & (zc  > Z20F));
        const unsigned long long m1 = __ballot((zc1 > evB.y) & (zc1 > Z20F));
        const unsigned long long m2 = __ballot((zc2 > evC.y) & (zc2 > Z20F));
        const unsigned long long m3 = __ballot((zc3 > evD.y) & (zc3 > Z20F));

        if (m0 != 0ull) {
            APPLY_EMIT(key);
            if (lane == 0) spkI[cnt] = key;
            ++cnt;
        } else if (m1 != 0ull) {
            A0 = A0p; A1 = A1p; B0 = B0p; B1 = B1p; zlim = zl1; ptr += 1;
            evA = evB; evB = evC; evC = evD; wA = wB; wB = wC; wC = wD;
            evD = evL[ptr + 3];
            LOADW(wD, __builtin_bit_cast(int, evD.x));
        } else if (m2 != 0ull) {
            A0 = A0q; A1 = A1q; B0 = B0q; B1 = B1q; zlim = zl2; ptr += 2;
            evA = evC; evB = evD; wA = wC; wB = wD;
            evC = evL[ptr + 2]; evD = evL[ptr + 3];
            LOADW(wC, __builtin_bit_cast(int, evC.x));
            LOADW(wD, __builtin_bit_cast(int, evD.x));
        } else if (m3 != 0ull) {
            A0 = A0r; A1 = A1r; B0 = B0r; B1 = B1r; zlim = zl3; ptr += 3;
            evA = evD; wA = wD;
            evB = evL[ptr + 1]; evC = evL[ptr + 2]; evD = evL[ptr + 3];
            LOADW(wB, __builtin_bit_cast(int, evB.x));
            LOADW(wC, __builtin_bit_cast(int, evC.x));
            LOADW(wD, __builtin_bit_cast(int, evD.x));
        } else {
            A0 = __builtin_fmaf(wD.x, evD.z, A0r);
            A1 = __builtin_fmaf(wD.y, evD.z, A1r);
            B0 = __builtin_fmaf(wD.x, evD.w, B0r);
            B1 = __builtin_fmaf(wD.y, evD.w, B1r);
            zlim = ZEPS * evD.y; ptr += 4;
            evA = evL[ptr + 0]; evB = evL[ptr + 1];
            evC = evL[ptr + 2]; evD = evL[ptr + 3];
            LOADW(wA, __builtin_bit_cast(int, evA.x));
            LOADW(wB, __builtin_bit_cast(int, evB.x));
            LOADW(wC, __builtin_bit_cast(int, evC.x));
            LOADW(wD, __builtin_bit_cast(int, evD.x));
        }
    }

    // ---- tail: single-step until inputs exhausted ----
    while (ptr < S_IN && cnt < MOUT) {
        const float zb0 = cand_z(A0, B0, zlim);
        const float zb1 = cand_z(A1, B1, zlim);
        const float zc = fmaxf(zb0, zb1);
        int key;
        REDUCE_KEY2(key, zb0, zb1);
        const unsigned long long m = __ballot((zc > evA.y) & (zc > Z20F));
        if (m != 0ull) {
            APPLY_EMIT(key);
            if (lane == 0) spkI[cnt] = key;
            ++cnt;
        } else {
            A0 = __builtin_fmaf(wA.x, evA.z, A0);
            A1 = __builtin_fmaf(wA.y, evA.z, A1);
            B0 = __builtin_fmaf(wA.x, evA.w, B0);
            B1 = __builtin_fmaf(wA.y, evA.w, B1);
            zlim = ZEPS * evA.y;
            ++ptr;
            evA = evB; evB = evC; evC = evD; wA = wB; wB = wC; wC = wD;
            evD = evL[ptr + 3];
            LOADW(wD, __builtin_bit_cast(int, evD.x));
        }
    }

    // ===== PHASE 2: pure emit drain — branchless 8-unrolled blocks =====
    // Frozen state self-poisons safely (zc->0, key zmax-bits <= KZ20, nan stays 0);
    // bogus sub-emits past the freeze point excluded via cnt += p.
    while (cnt < MOUT) {
        int k0, k1, k2, k3, k4, k5, k6, k7;
        EMIT_STEP(k0); EMIT_STEP(k1); EMIT_STEP(k2); EMIT_STEP(k3);
        EMIT_STEP(k4); EMIT_STEP(k5); EMIT_STEP(k6); EMIT_STEP(k7);
        if (lane == 0) {
            spkI[cnt + 0] = k0; spkI[cnt + 1] = k1;
            spkI[cnt + 2] = k2; spkI[cnt + 3] = k3;
            spkI[cnt + 4] = k4; spkI[cnt + 5] = k5;
            spkI[cnt + 6] = k6; spkI[cnt + 7] = k7;
        }
        const bool f0 = (k0 & ~127) <= KZ20;
        const bool f1 = (k1 & ~127) <= KZ20;
        const bool f2 = (k2 & ~127) <= KZ20;
        const bool f3 = (k3 & ~127) <= KZ20;
        const bool f4 = (k4 & ~127) <= KZ20;
        const bool f5 = (k5 & ~127) <= KZ20;
        const bool f6 = (k6 & ~127) <= KZ20;
        const bool f7 = (k7 & ~127) <= KZ20;
        const int p = f0 ? 0 : (f1 ? 1 : (f2 ? 2 : (f3 ? 3 :
                      (f4 ? 4 : (f5 ? 5 : (f6 ? 6 : (f7 ? 7 : 8)))))));
        cnt += p;
        if (p < 8) break;
    }
    if (cnt > MOUT) cnt = MOUT;
#undef LOADW
#undef REDUCE_KEY2
#undef APPLY_EMIT
#undef EMIT_STEP

    // ---- flush: decode keys -> (t, id), fill the rest (every call) ----
    __syncthreads();
    for (int k = lane; k < MOUT; k += 64) {
        const int kk = spkI[k];
        const bool live = (k < cnt);
        const float zmax = __builtin_bit_cast(float, kk & ~127);
        const float t = NL2 * hw_log2(zmax);
        const float id = (float)(127 - (kk & 127));
        out_t[b * MOUT + k]  = live ? t : NO_SPIKE_T;
        out_id[b * MOUT + k] = live ? id : -1.0f;
    }
}

} // namespace

extern "C" void kernel_launch(void* const* d_in, const int* in_sizes, int n_in,
                              void* d_out, int out_size, void* d_ws, size_t ws_size,
                              hipStream_t stream) {
    (void)in_sizes; (void)n_in; (void)out_size;
    const float* in_t   = (const float*)d_in[0];
    const int*   in_sid = (const int*)d_in[1];
    const float* wff    = (const float*)d_in[2];
    const float* wrec   = (const float*)d_in[3];

    float* out_t  = (float*)d_out;
    float* out_id = (float*)d_out + BATCH * MOUT;

    float* wffT = (float*)d_ws;
    const size_t need = (size_t)(NSYN * NNEUR) * sizeof(float);
    const int use_t = (ws_size >= need) ? 1 : 0;

    if (use_t) {
        transpose_wff_kernel<<<(NSYN * NNEUR) / 256, 256, 0, stream>>>(wff, wffT);
    }
    lif_event_kernel<<<BATCH, 64, LDS_TOTAL, stream>>>(in_t, in_sid, wff, wffT, wrec,
                                                       use_t, out_t, out_id);
}